// Round 11
// baseline (846623.340 us; speedup 1.0000x reference)
//
#include <hip/hip_runtime.h>
#include <math.h>

// DistillerGRU: T=512, B=64, H=1024, 2 layers.
// R11 = R10 with all inline-asm memory ops switched to the 64-bit
// VGPR-address form (fixes the "s"-constraint-on-divergent-PHI compile error).
//  - 256 WGs, 8 groups = layer(2) x batch-quarter(4), 32 WGs each; round-robin
//    dispatch puts each group on ONE XCD (verified via HW_REG_XCC_ID;
//    unbalanced -> static groups).
//  - sc0 (L2-scope) vs agent (L3-scope) decided by RUNTIME PROBE (warm L1 ->
//    remote sc0 store -> re-read; consensus-AND). Fast polls demote to agent
//    after ~1M spins (same-XCD agent reads traverse local L2; always safe).
//  - Inter-layer L0->L1: 32-slot ring + agent flags (R7-proven protocol).
//  - Per WG: 16 batch rows x 32 h-cols; 4 waves split K=2048; weights
//    12 K-steps in VGPR + 4 in LDS per wave; 96 MFMAs/wave/step.

#define TT 512
#define BB 64
#define HH 1024
#define NWG 256
#define NBH (BB * HH)
#define RING 32
#define MAGICV 0x5CA1AB1Eu

typedef _Float16 half8 __attribute__((ext_vector_type(8)));
typedef _Float16 f16x4 __attribute__((ext_vector_type(4)));
typedef float f32x4 __attribute__((ext_vector_type(4)));
typedef unsigned int u32x4 __attribute__((ext_vector_type(4)));
typedef unsigned long long u64;

#define MFMA16 __builtin_amdgcn_mfma_f32_16x16x32_f16

// ---------------- asm memory helpers (64-bit VGPR address form) ----------------
// mode: 0 = plain (read-only), 1 = sc0 (probe-verified XCD-local), 2 = agent
__device__ inline u32x4 ldq(const void* p, int mode) {
  u32x4 r; u64 a = (u64)(uintptr_t)p;
  if (mode == 0)
    asm volatile("global_load_dwordx4 %0, %1, off" : "=v"(r) : "v"(a));
  else if (mode == 1)
    asm volatile("global_load_dwordx4 %0, %1, off sc0" : "=v"(r) : "v"(a));
  else
    asm volatile("global_load_dwordx4 %0, %1, off sc0 sc1" : "=v"(r) : "v"(a));
  return r;
}
__device__ inline unsigned ldflag(const void* p, bool loc) {
  unsigned r; u64 a = (u64)(uintptr_t)p;
  if (loc)
    asm volatile("global_load_dword %0, %1, off sc0\n\ts_waitcnt vmcnt(0)"
                 : "=v"(r) : "v"(a) : "memory");
  else
    asm volatile("global_load_dword %0, %1, off sc0 sc1\n\ts_waitcnt vmcnt(0)"
                 : "=v"(r) : "v"(a) : "memory");
  return r;
}
__device__ inline void stw(void* p, unsigned v, bool loc) {
  u64 a = (u64)(uintptr_t)p;
  if (loc)
    asm volatile("global_store_dword %0, %1, off sc0" :: "v"(a), "v"(v) : "memory");
  else
    asm volatile("global_store_dword %0, %1, off sc0 sc1" :: "v"(a), "v"(v) : "memory");
}
__device__ inline void vdrain() { asm volatile("s_waitcnt vmcnt(0)" ::: "memory"); }

__device__ inline float fast_sigmoid(float x) { return 1.f / (1.f + __expf(-x)); }
__device__ inline float fast_tanh(float x) {
  float e = __expf(2.f * x);
  return 1.f - 2.f / (e + 1.f);
}
__device__ inline void backoff_sleep(int sl) {   // literal-only s_sleep
  if (sl <= 0) __builtin_amdgcn_s_sleep(1);
  else if (sl == 1) __builtin_amdgcn_s_sleep(2);
  else if (sl == 2) __builtin_amdgcn_s_sleep(4);
  else __builtin_amdgcn_s_sleep(8);
}

// ---------------- prologue kernels ----------------
__global__ void cvt_f32_f16_kernel(const float* __restrict__ src,
                                   _Float16* __restrict__ dst, long n) {
  long i = ((long)blockIdx.x * blockDim.x + threadIdx.x) * 4;
  long stride = (long)gridDim.x * blockDim.x * 4;
  for (long e = i; e < n; e += stride) {
    float4 v = *(const float4*)(src + e);
    f16x4 h;
    h.x = (_Float16)v.x; h.y = (_Float16)v.y;
    h.z = (_Float16)v.z; h.w = (_Float16)v.w;
    *(f16x4*)(dst + e) = h;
  }
}

// wp[tile(192)][kst(64)][lane(64)][8]; element = W[tile*16+(lane&15)][k],
// k = kst*32 + (lane>>4)*8 + sub; kst<32 from Wh, kst>=32 from Wx.
__global__ void cvt_wpack_kernel(const float* __restrict__ Wh,
                                 const float* __restrict__ Wx,
                                 _Float16* __restrict__ wp) {
  int gid = blockIdx.x * 256 + threadIdx.x;
  int lane = gid & 63;
  int kst = (gid >> 6) & 63;
  int tile = gid >> 12;
  int g = tile * 16 + (lane & 15);
  int ko = (lane >> 4) * 8;
  const float* src = (kst < 32) ? (Wh + (long)g * HH + kst * 32 + ko)
                                : (Wx + (long)g * HH + (kst - 32) * 32 + ko);
  half8 h;
#pragma unroll
  for (int j = 0; j < 8; ++j) h[j] = (_Float16)src[j];
  *(half8*)(wp + (((long)tile * 64 + kst) * 64 + lane) * 8) = h;
}

__global__ void init_hf_kernel(const float* __restrict__ h0,
                               _Float16* __restrict__ h0loc,
                               _Float16* __restrict__ h1loc) {
  int i = blockIdx.x * 256 + threadIdx.x;  // grid = 2*B*H/256
  float v = h0[i];
  if (i < NBH) h0loc[i] = (_Float16)v;
  else         h1loc[i - NBH] = (_Float16)v;
}

__global__ void sentinel_kernel(float* out) { out[0] = 12345.0f; }

// ---------------- persistent 2-layer GRU ----------------
__global__ __launch_bounds__(256, 1) void gru_persist(
    const _Float16* __restrict__ x16,
    const _Float16* __restrict__ w0p, const _Float16* __restrict__ w1p,
    const float* __restrict__ bx0, const float* __restrict__ bh0,
    const float* __restrict__ bx1, const float* __restrict__ bh1,
    const float* __restrict__ h0in,
    _Float16* __restrict__ h0loc, _Float16* __restrict__ h1loc,
    _Float16* __restrict__ hist,
    float* __restrict__ out, unsigned* __restrict__ bar)
{
  const int tid = threadIdx.x;
  const int wid = tid >> 6, lane = tid & 63;
  const int wg = blockIdx.x;
  const int lcol = lane & 15;
  const int lk = (lane >> 4) * 8;

  __shared__ unsigned short xarr[NWG];
  __shared__ unsigned meta[4];
  __shared__ u32x4 wlds[4][6][4][64];   // 96KB
  __shared__ f32x4 red[4][6][64];       // 24KB
  __shared__ f32x4 yshare[2][64];       // 2KB
  __shared__ unsigned rdy[2];

  // ---- discovery: XCD id, group membership ----
  unsigned xcc;
  asm volatile("s_getreg_b32 %0, hwreg(20, 0, 32)" : "=s"(xcc));
  {
    unsigned* xslot = bar + 8192;
    if (tid == 0) stw(xslot + wg, xcc + 1, false);
    if (wid == 0) {
      unsigned v[4];
      for (;;) {
        bool ok = true;
#pragma unroll
        for (int j = 0; j < 4; ++j) {
          v[j] = ldflag(xslot + lane * 4 + j, false);
          ok = ok && (v[j] != 0);
        }
        if (__ballot(ok) == ~0ull) break;
        __builtin_amdgcn_s_sleep(8);
      }
#pragma unroll
      for (int j = 0; j < 4; ++j) xarr[lane * 4 + j] = (unsigned short)(v[j] - 1);
      if (lane == 0) {
        int cnt[8] = {0,0,0,0,0,0,0,0};
        int rank = 0; bool okx = true;
        const unsigned me = xcc;
        for (int j = 0; j < NWG; ++j) {
          unsigned xv = xarr[j];
          if (xv > 7u) { okx = false; break; }
          cnt[xv]++;
          if (j < wg && xv == me) rank++;
        }
        bool bal = okx;
        if (okx) for (int j = 0; j < 8; ++j) bal = bal && (cnt[j] == 32);
        if (bal) { meta[0] = me >> 2; meta[1] = me & 3; meta[2] = (unsigned)rank; }
        else { meta[0] = (unsigned)(wg >> 7); meta[1] = (unsigned)((wg >> 5) & 3);
               meta[2] = (unsigned)(wg & 31); }
      }
    }
    if (tid == 0) { rdy[0] = 0; rdy[1] = 0; meta[3] = 0; }
    __syncthreads();
  }
  const int layer = (int)meta[0];
  const int q = (int)meta[1];
  const int rank = (int)meta[2];
  const int lg = layer * 4 + q;

  unsigned* myf  = bar + lg * 1024;
  unsigned* l0if = bar + 8704 + q * 1024;
  unsigned* prog = bar + 12800 + q * 1024;
  unsigned* prb  = bar + 17408 + lg * 512;

  // ---- probe: does an sc0 load see another CU's sc0 store? (consensus) ----
  if (wid == 0) {
    (void)ldflag(prb, true);                            // warm this CU's L1 (reads 0)
    if (lane == 0) stw(prb + 32 + rank * 4, 1u, false); // arrive
    if (rank == 0) {
      int sl = 0;
      for (;;) {
        unsigned f = ldflag(prb + 32 + (lane & 31) * 4, false);
        if (__ballot(f != 0) == ~0ull) break;
        backoff_sleep(sl); ++sl;
      }
      if (lane == 0) {
        stw(prb, MAGICV, true);                         // sc0 store (L2)
        vdrain();
        stw(prb + 16, 1u, false);                       // ready (agent)
      }
    }
    {
      int sl = 0;
      while (ldflag(prb + 16, false) == 0) { backoff_sleep(sl); ++sl; }
    }
    unsigned pv = ldflag(prb, true);                    // L1-warmed re-read
    unsigned verdict = (pv == MAGICV) ? 3u : 2u;
    if (lane == 0) stw(prb + 160 + rank * 4, verdict, false);
    int sl = 0;
    unsigned f;
    for (;;) {
      f = ldflag(prb + 160 + (lane & 31) * 4, false);
      if (__ballot(f >= 2u) == ~0ull) break;
      backoff_sleep(sl); ++sl;
    }
    bool allfast = (__ballot(f == 3u) == ~0ull);
    if (lane == 0) meta[3] = allfast ? 1u : 0u;
  }
  __syncthreads();
  const bool fast = meta[3] != 0;

  // ---- weights: WG owns 32 cols (2 col-tiles) x 3 gates = 6 tiles ----
  const _Float16* wf = layer ? w1p : w0p;
  _Float16* hloc = layer ? h1loc : h0loc;
  half8 wb[6][12];
#pragma unroll
  for (int i = 0; i < 6; ++i) {
    const long tile = (long)((i >> 1) * 64 + rank * 2 + (i & 1));
#pragma unroll
    for (int ks = 0; ks < 12; ++ks)
      wb[i][ks] = *(const half8*)(wf + (tile * 64 + (wid * 16 + ks)) * 512 + lane * 8);
#pragma unroll
    for (int jj = 0; jj < 4; ++jj)
      wlds[wid][i][jj][lane] = *(const u32x4*)(wf + (tile * 64 + (wid * 16 + 12 + jj)) * 512 + lane * 8);
  }

  const int er0 = q * 16 + (lane >> 4) * 4;     // 4 batch rows (within quarter)
  const int col = rank * 32 + wid * 16 + lcol;  // valid for wid<2
  float rbv = 0.f, zbv = 0.f, nhb = 0.f, nxb = 0.f;
  float hreg[4] = {0.f, 0.f, 0.f, 0.f};
  if (wid < 2) {
    const float* bx = layer ? bx1 : bx0;
    const float* bhp = layer ? bh1 : bh0;
    rbv = bhp[col] + bx[col];
    zbv = bhp[HH + col] + bx[HH + col];
    nhb = bhp[2 * HH + col];
    nxb = bx[2 * HH + col];
#pragma unroll
    for (int j = 0; j < 4; ++j)
      hreg[j] = h0in[layer * NBH + (er0 + j) * HH + col];
  }
  __syncthreads();   // wlds ready

  // per-lane byte offset of this wave's A-fragment chunk 0
  const long aoff = (long)(((q * 16 + lcol) * HH) + (wid & 1) * 512 + lk) * 2;

  int lb = 0, guard = 0;
  bool uf = fast;    // fast-poll mode with demotion guard
  for (int t = 0; t < TT; ++t) {
    const int rd = t & 1;
    const char* ap; int amode;

    if (wid < 2) {
      if (t > 0) {
        if (wid == 0) {
          int sl = 0;
          for (;;) {
            unsigned f = ldflag(myf + (lane & 31) * 16, uf);
            if (__ballot((int)f >= t) == ~0ull) break;
            backoff_sleep(sl); ++sl;
            if (++guard > (1 << 20)) uf = false;   // safety demotion
          }
          if (lane == 0)
            __hip_atomic_store(&rdy[0], (unsigned)t, __ATOMIC_RELEASE, __HIP_MEMORY_SCOPE_WORKGROUP);
        } else {
          while (__hip_atomic_load(&rdy[0], __ATOMIC_ACQUIRE, __HIP_MEMORY_SCOPE_WORKGROUP) < (unsigned)t)
            __builtin_amdgcn_s_sleep(1);
        }
        asm volatile("" ::: "memory");
      }
      ap = (const char*)(hloc + (long)rd * NBH) + aoff;
      amode = fast ? 1 : 2;
    } else if (layer == 0) {
      ap = (const char*)(x16 + (long)t * NBH) + aoff;
      amode = 0;
    } else {
      if (wid == 2) {
        int sl = 0;
        for (;;) {
          unsigned f = ldflag(l0if + (lane & 31) * 16, false);
          if (__ballot((int)f >= t + 1) == ~0ull) break;
          backoff_sleep(sl); ++sl;
        }
        if (lane == 0)
          __hip_atomic_store(&rdy[1], (unsigned)(t + 1), __ATOMIC_RELEASE, __HIP_MEMORY_SCOPE_WORKGROUP);
      } else {
        while (__hip_atomic_load(&rdy[1], __ATOMIC_ACQUIRE, __HIP_MEMORY_SCOPE_WORKGROUP) < (unsigned)(t + 1))
          __builtin_amdgcn_s_sleep(1);
      }
      asm volatile("" ::: "memory");
      ap = (const char*)(hist + (long)((t + 1) & (RING - 1)) * NBH) + aoff;
      amode = 2;
    }

    // ---- A-fragment loads: issue 16, single drain ----
    u32x4 ab[16];
#pragma unroll
    for (int ks = 0; ks < 16; ++ks) ab[ks] = ldq(ap + ks * 64, amode);
    asm volatile("s_waitcnt vmcnt(0)" ::: "memory");
    __builtin_amdgcn_sched_barrier(0);

    // ---- 96 MFMAs: 6 tiles x 16 ks ----
    f32x4 acc[6] = {};
#pragma unroll
    for (int ks = 0; ks < 12; ++ks) {
      half8 a = __builtin_bit_cast(half8, ab[ks]);
#pragma unroll
      for (int i = 0; i < 6; ++i) acc[i] = MFMA16(a, wb[i][ks], acc[i], 0, 0, 0);
    }
#pragma unroll
    for (int jj = 0; jj < 4; ++jj) {
      half8 a = __builtin_bit_cast(half8, ab[12 + jj]);
#pragma unroll
      for (int i = 0; i < 6; ++i)
        acc[i] = MFMA16(a, __builtin_bit_cast(half8, wlds[wid][i][jj][lane]), acc[i], 0, 0, 0);
    }
#pragma unroll
    for (int i = 0; i < 6; ++i) red[wid][i][lane] = acc[i];
    __syncthreads();   // (A)

    if (wid < 2) {
      const int h = wid;   // col-tile this wave finishes
      f32x4 rs = red[0][h][lane] + red[1][h][lane] + red[2][h][lane] + red[3][h][lane];
      f32x4 zs = red[0][2 + h][lane] + red[1][2 + h][lane] + red[2][2 + h][lane] + red[3][2 + h][lane];
      f32x4 nh = red[0][4 + h][lane] + red[1][4 + h][lane];
      f32x4 nx = red[2][4 + h][lane] + red[3][4 + h][lane];
      char* hdst = (char*)(hloc + (long)(rd ^ 1) * NBH);
      f32x4 hnv;
#pragma unroll
      for (int j = 0; j < 4; ++j) {
        const float rg = fast_sigmoid(rs[j] + rbv);
        const float zg = fast_sigmoid(zs[j] + zbv);
        const float ng = fast_tanh(nx[j] + nxb + rg * (nh[j] + nhb));
        const float hn = (1.f - zg) * ng + zg * hreg[j];
        hreg[j] = hn; hnv[j] = hn;
      }
      yshare[h][lane] = hnv;
#pragma unroll
      for (int j = 0; j < 4; ++j) {
        _Float16 hf = (_Float16)hnv[j];
        unsigned us = (unsigned)__builtin_bit_cast(unsigned short, hf);
        unsigned other = (unsigned)__shfl_xor((int)us, 1);
        if ((lane & 1) == 0)
          stw(hdst + (long)(((er0 + j) * HH) + col) * 2, us | (other << 16), fast);
      }
      vdrain();   // this wave's h-stores in L2/L3 before syncB
    }
    __syncthreads();   // (B)
    if (tid == 0) stw(myf + rank * 16, (unsigned)(t + 1), fast);

    if (layer == 0) {
      if (wid == 2) {
        vdrain();                                        // ring stores of t-1 done
        stw(l0if + rank * 16, (unsigned)t, false);       // slots <= t valid
        if (t >= RING - 1) {                             // lazy back-pressure
          const int need = t - (RING - 1);
          if (lb < need) {
            int sl = 0;
            for (;;) {
              unsigned f = ldflag(prog + (lane & 31) * 16, false);
              if (__ballot((int)f >= need + 16) == ~0ull) { lb = need + 16; break; }
              if (__ballot((int)f >= need) == ~0ull) { lb = need; break; }
              backoff_sleep(sl); ++sl;
            }
          }
        }
        char* rbase = (char*)(hist + (long)((t + 1) & (RING - 1)) * NBH);
#pragma unroll
        for (int h2 = 0; h2 < 2; ++h2) {
          f32x4 v = yshare[h2][lane];
          const int coln = rank * 32 + h2 * 16 + lcol;
#pragma unroll
          for (int j = 0; j < 4; ++j) {
            _Float16 hf = (_Float16)v[j];
            unsigned us = (unsigned)__builtin_bit_cast(unsigned short, hf);
            unsigned other = (unsigned)__shfl_xor((int)us, 1);
            if ((lane & 1) == 0)
              stw(rbase + (long)(((er0 + j) * HH) + coln) * 2, us | (other << 16), false);
          }
        }
      }
    } else {
      if (wid == 2 && lane == 0)
        stw(prog + rank * 16, (unsigned)t, false);       // L1 progress
      if (wid == 3) {
        float* yo = out + (long)t * NBH;
#pragma unroll
        for (int h2 = 0; h2 < 2; ++h2) {
          f32x4 v = yshare[h2][lane];
          const int coln = rank * 32 + h2 * 16 + lcol;
#pragma unroll
          for (int j = 0; j < 4; ++j) yo[(er0 + j) * HH + coln] = v[j];
        }
      }
    }
  }

  if (layer == 0 && wid == 2) {          // certify final ring slot
    vdrain();
    stw(l0if + rank * 16, (unsigned)TT, false);
  }
  if (wid < 2) {                         // final hidden states (f32 master)
#pragma unroll
    for (int j = 0; j < 4; ++j)
      out[(long)TT * NBH + (long)layer * NBH + (er0 + j) * HH + col] = hreg[j];
  }
}

// ---------------- launch ----------------
extern "C" void kernel_launch(void* const* d_in, const int* in_sizes, int n_in,
                              void* d_out, int out_size, void* d_ws, size_t ws_size,
                              hipStream_t stream) {
  const float* x   = (const float*)d_in[0];
  const float* h0  = (const float*)d_in[1];
  const float* Wx0 = (const float*)d_in[2];
  const float* bx0 = (const float*)d_in[3];
  const float* Wh0 = (const float*)d_in[4];
  const float* bh0 = (const float*)d_in[5];
  const float* Wx1 = (const float*)d_in[6];
  const float* bx1 = (const float*)d_in[7];
  const float* Wh1 = (const float*)d_in[8];
  const float* bh1 = (const float*)d_in[9];
  float* out = (float*)d_out;

  const long nTBH = (long)TT * BB * HH;
  const long nWP  = (long)192 * 64 * 64 * 8;

  char* p = (char*)d_ws;
  _Float16* x16   = (_Float16*)p;  p += nTBH * 2;              // 67.1 MB
  _Float16* w0p   = (_Float16*)p;  p += nWP * 2;               // 12.6 MB
  _Float16* w1p   = (_Float16*)p;  p += nWP * 2;               // 12.6 MB
  _Float16* hist  = (_Float16*)p;  p += (long)RING * NBH * 2;  // 4.2 MB
  _Float16* h0loc = (_Float16*)p;  p += 2 * (long)NBH * 2;     // 256 KB
  _Float16* h1loc = (_Float16*)p;  p += 2 * (long)NBH * 2;     // 256 KB
  unsigned* bar   = (unsigned*)p;  p += 131072;                // 128 KB flags
  if ((size_t)(p - (char*)d_ws) > ws_size) {
    sentinel_kernel<<<1, 1, 0, stream>>>(out);
    return;
  }

  (void)hipMemsetAsync(bar, 0, 131072, stream);
  cvt_f32_f16_kernel<<<2048, 256, 0, stream>>>(x, x16, nTBH);
  cvt_wpack_kernel<<<3072, 256, 0, stream>>>(Wh0, Wx0, w0p);
  cvt_wpack_kernel<<<3072, 256, 0, stream>>>(Wh1, Wx1, w1p);
  init_hf_kernel<<<512, 256, 0, stream>>>(h0, h0loc, h1loc);

  void* args[] = {(void*)&x16, (void*)&w0p, (void*)&w1p,
                  (void*)&bx0, (void*)&bh0, (void*)&bx1, (void*)&bh1,
                  (void*)&h0, (void*)&h0loc, (void*)&h1loc, (void*)&hist,
                  (void*)&out, (void*)&bar};
  hipError_t e = hipLaunchCooperativeKernel((const void*)gru_persist,
                                            dim3(NWG), dim3(256), args, 0, stream);
  if (e != hipSuccess) {
    // 256 WGs at 1 WG/CU: co-resident on an idle device even without coop.
    gru_persist<<<NWG, 256, 0, stream>>>(x16, w0p, w1p, bx0, bh0, bx1, bh1,
                                         h0, h0loc, h1loc, hist, out, bar);
  }
}

// Round 12
// 2634.447 us; speedup vs baseline: 321.3666x; 321.3666x over previous
//
#include <hip/hip_runtime.h>
#include <math.h>

// DistillerGRU: T=512, B=64, H=1024, 2 layers.
// R12: persistent cooperative kernel. R7-proven AGENT-scope protocol
// (sc0-only sync proven broken in R11: flags stall ~1ms in the CU write path).
//  - 8 groups of 32 WGs: (layer, batch-quarter). Batch rows independent ->
//    groups fully decoupled except one-way L0->L1 ring.
//  - Per WG: 16 batch rows x 32 h-cols (2 col-tiles x 3 gates = 6 MFMA tiles
//    per wave); 4 waves split K=2048; weights 12 K-steps VGPR + 4 LDS.
//  - Per-wave EARLY flags: waves 0/1 certify their own 16 cols right after
//    their h-store drain (no syncthreads/tid0 relay on the flag path).
//  - Every consumer wave polls flags directly (no LDS relay), s_sleep(1).
//  - L0->L1: 32-slot ring + flags + lazy back-pressure (R7/R11-proven).

#define TT 512
#define BB 64
#define HH 1024
#define NWG 256
#define NBH (BB * HH)
#define RING 32

typedef _Float16 half8 __attribute__((ext_vector_type(8)));
typedef _Float16 f16x4 __attribute__((ext_vector_type(4)));
typedef float f32x4 __attribute__((ext_vector_type(4)));
typedef unsigned int u32x4 __attribute__((ext_vector_type(4)));
typedef unsigned long long u64;

#define MFMA16 __builtin_amdgcn_mfma_f32_16x16x32_f16

// ---------------- asm memory helpers (64-bit VGPR-address form) ----------------
__device__ inline u32x4 ldq_plain(const void* p) {
  u32x4 r; u64 a = (u64)(uintptr_t)p;
  asm volatile("global_load_dwordx4 %0, %1, off" : "=v"(r) : "v"(a));
  return r;
}
__device__ inline u32x4 ldq_agent(const void* p) {
  u32x4 r; u64 a = (u64)(uintptr_t)p;
  asm volatile("global_load_dwordx4 %0, %1, off sc0 sc1" : "=v"(r) : "v"(a));
  return r;
}
__device__ inline unsigned ldflag(const void* p) {   // agent-scope flag read
  unsigned r; u64 a = (u64)(uintptr_t)p;
  asm volatile("global_load_dword %0, %1, off sc0 sc1\n\ts_waitcnt vmcnt(0)"
               : "=v"(r) : "v"(a) : "memory");
  return r;
}
__device__ inline void stw(void* p, unsigned v) {    // agent-scope store
  u64 a = (u64)(uintptr_t)p;
  asm volatile("global_store_dword %0, %1, off sc0 sc1" :: "v"(a), "v"(v) : "memory");
}
__device__ inline void vdrain() { asm volatile("s_waitcnt vmcnt(0)" ::: "memory"); }

__device__ inline float fast_sigmoid(float x) { return 1.f / (1.f + __expf(-x)); }
__device__ inline float fast_tanh(float x) {
  float e = __expf(2.f * x);
  return 1.f - 2.f / (e + 1.f);
}
__device__ inline void backoff_sleep(int sl) {   // literal-only s_sleep
  if (sl <= 0) __builtin_amdgcn_s_sleep(1);
  else if (sl == 1) __builtin_amdgcn_s_sleep(2);
  else if (sl == 2) __builtin_amdgcn_s_sleep(4);
  else __builtin_amdgcn_s_sleep(8);
}

// ---------------- prologue kernels ----------------
__global__ void cvt_f32_f16_kernel(const float* __restrict__ src,
                                   _Float16* __restrict__ dst, long n) {
  long i = ((long)blockIdx.x * blockDim.x + threadIdx.x) * 4;
  long stride = (long)gridDim.x * blockDim.x * 4;
  for (long e = i; e < n; e += stride) {
    float4 v = *(const float4*)(src + e);
    f16x4 h;
    h.x = (_Float16)v.x; h.y = (_Float16)v.y;
    h.z = (_Float16)v.z; h.w = (_Float16)v.w;
    *(f16x4*)(dst + e) = h;
  }
}

// wp[tile(192)][kst(64)][lane(64)][8]; element = W[tile*16+(lane&15)][k],
// k = kst*32 + (lane>>4)*8 + sub; kst<32 from Wh, kst>=32 from Wx.
__global__ void cvt_wpack_kernel(const float* __restrict__ Wh,
                                 const float* __restrict__ Wx,
                                 _Float16* __restrict__ wp) {
  int gid = blockIdx.x * 256 + threadIdx.x;
  int lane = gid & 63;
  int kst = (gid >> 6) & 63;
  int tile = gid >> 12;
  int g = tile * 16 + (lane & 15);
  int ko = (lane >> 4) * 8;
  const float* src = (kst < 32) ? (Wh + (long)g * HH + kst * 32 + ko)
                                : (Wx + (long)g * HH + (kst - 32) * 32 + ko);
  half8 h;
#pragma unroll
  for (int j = 0; j < 8; ++j) h[j] = (_Float16)src[j];
  *(half8*)(wp + (((long)tile * 64 + kst) * 64 + lane) * 8) = h;
}

__global__ void init_hf_kernel(const float* __restrict__ h0,
                               _Float16* __restrict__ h0loc,
                               _Float16* __restrict__ h1loc) {
  int i = blockIdx.x * 256 + threadIdx.x;  // grid = 2*B*H/256
  float v = h0[i];
  if (i < NBH) h0loc[i] = (_Float16)v;
  else         h1loc[i - NBH] = (_Float16)v;
}

__global__ void sentinel_kernel(float* out) { out[0] = 12345.0f; }

// ---------------- persistent 2-layer GRU ----------------
__global__ __launch_bounds__(256, 1) void gru_persist(
    const _Float16* __restrict__ x16,
    const _Float16* __restrict__ w0p, const _Float16* __restrict__ w1p,
    const float* __restrict__ bx0, const float* __restrict__ bh0,
    const float* __restrict__ bx1, const float* __restrict__ bh1,
    const float* __restrict__ h0in,
    _Float16* __restrict__ h0loc, _Float16* __restrict__ h1loc,
    _Float16* __restrict__ hist,
    float* __restrict__ out, unsigned* __restrict__ bar)
{
  const int tid = threadIdx.x;
  const int wid = tid >> 6, lane = tid & 63;
  const int wg = blockIdx.x;
  const int lcol = lane & 15;
  const int lk = (lane >> 4) * 8;

  const int grp = wg >> 5;          // 0..7
  const int layer = grp >> 2;
  const int q = grp & 3;
  const int rank = wg & 31;

  __shared__ u32x4 wlds[4][6][4][64];   // 96KB: per-wave kst 12..15 weights
  __shared__ f32x4 red[4][6][64];       // 24KB
  __shared__ f32x4 yshare[2][64];       // 2KB

  unsigned* myf  = bar + grp * 1024;            // 64 slots x 64B stride
  unsigned* l0if = bar + 8192 + q * 1024;       // ring-valid flags (32 slots)
  unsigned* prog = bar + 12288 + q * 1024;      // L1 progress (32 slots)

  // ---- weights: WG owns 32 cols (2 col-tiles) x 3 gates = 6 tiles ----
  const _Float16* wf = layer ? w1p : w0p;
  _Float16* hloc = layer ? h1loc : h0loc;
  half8 wb[6][12];
#pragma unroll
  for (int i = 0; i < 6; ++i) {
    const long tile = (long)((i >> 1) * 64 + rank * 2 + (i & 1));
#pragma unroll
    for (int ks = 0; ks < 12; ++ks)
      wb[i][ks] = *(const half8*)(wf + (tile * 64 + (wid * 16 + ks)) * 512 + lane * 8);
#pragma unroll
    for (int jj = 0; jj < 4; ++jj)
      wlds[wid][i][jj][lane] = *(const u32x4*)(wf + (tile * 64 + (wid * 16 + 12 + jj)) * 512 + lane * 8);
  }

  const int er0 = q * 16 + (lane >> 4) * 4;     // 4 batch rows (global row ids)
  const int col = rank * 32 + wid * 16 + lcol;  // valid for wid<2
  float rbv = 0.f, zbv = 0.f, nhb = 0.f, nxb = 0.f;
  float hreg[4] = {0.f, 0.f, 0.f, 0.f};
  if (wid < 2) {
    const float* bx = layer ? bx1 : bx0;
    const float* bhp = layer ? bh1 : bh0;
    rbv = bhp[col] + bx[col];
    zbv = bhp[HH + col] + bx[HH + col];
    nhb = bhp[2 * HH + col];
    nxb = bx[2 * HH + col];
#pragma unroll
    for (int j = 0; j < 4; ++j)
      hreg[j] = h0in[layer * NBH + (er0 + j) * HH + col];
  }
  __syncthreads();   // wlds ready

  // per-lane byte offset of this wave's A-fragment chunk 0
  const long aoff = (long)(((q * 16 + lcol) * HH) + (wid & 1) * 512 + lk) * 2;

  int lb = 0;   // wave2(L0): lazy lower bound on L1 progress
  for (int t = 0; t < TT; ++t) {
    const int rd = t & 1;
    u32x4 ab[16];

    if (wid < 2) {
      // ---- wait: own group finished step t-1 (both h-waves poll directly) ----
      if (t > 0) {
        for (;;) {
          unsigned f = ldflag(myf + lane * 16);          // 64 slots, 1/lane
          if (__ballot((int)f >= t) == ~0ull) break;
          __builtin_amdgcn_s_sleep(1);
        }
        asm volatile("" ::: "memory");
      }
      const char* ap = (const char*)(hloc + (long)rd * NBH) + aoff;
#pragma unroll
      for (int ks = 0; ks < 16; ++ks) ab[ks] = ldq_agent(ap + ks * 64);
    } else if (layer == 0) {
      const char* ap = (const char*)(x16 + (long)t * NBH) + aoff;
#pragma unroll
      for (int ks = 0; ks < 16; ++ks) ab[ks] = ldq_plain(ap + ks * 64);
    } else {
      // y0[t] = ring slot t+1: both x-waves poll producer flags directly
      for (;;) {
        unsigned f = ldflag(l0if + (lane & 31) * 16);    // 32 slots
        if (__ballot((int)f >= t + 1) == ~0ull) break;
        __builtin_amdgcn_s_sleep(1);
      }
      asm volatile("" ::: "memory");
      const char* ap = (const char*)(hist + (long)((t + 1) & (RING - 1)) * NBH) + aoff;
#pragma unroll
      for (int ks = 0; ks < 16; ++ks) ab[ks] = ldq_agent(ap + ks * 64);
    }
    asm volatile("s_waitcnt vmcnt(0)" ::: "memory");
    __builtin_amdgcn_sched_barrier(0);

    // ---- 96 MFMAs: 6 tiles x 16 ks ----
    f32x4 acc[6] = {};
#pragma unroll
    for (int ks = 0; ks < 12; ++ks) {
      half8 a = __builtin_bit_cast(half8, ab[ks]);
#pragma unroll
      for (int i = 0; i < 6; ++i) acc[i] = MFMA16(a, wb[i][ks], acc[i], 0, 0, 0);
    }
#pragma unroll
    for (int jj = 0; jj < 4; ++jj) {
      half8 a = __builtin_bit_cast(half8, ab[12 + jj]);
#pragma unroll
      for (int i = 0; i < 6; ++i)
        acc[i] = MFMA16(a, __builtin_bit_cast(half8, wlds[wid][i][jj][lane]), acc[i], 0, 0, 0);
    }
#pragma unroll
    for (int i = 0; i < 6; ++i) red[wid][i][lane] = acc[i];
    __syncthreads();   // (A)

    if (wid < 2) {
      const int h = wid;   // col-tile this wave finishes
      f32x4 rs = red[0][h][lane] + red[1][h][lane] + red[2][h][lane] + red[3][h][lane];
      f32x4 zs = red[0][2 + h][lane] + red[1][2 + h][lane] + red[2][2 + h][lane] + red[3][2 + h][lane];
      f32x4 nh = red[0][4 + h][lane] + red[1][4 + h][lane];
      f32x4 nx = red[2][4 + h][lane] + red[3][4 + h][lane];
      char* hdst = (char*)(hloc + (long)(rd ^ 1) * NBH);
      f32x4 hnv;
#pragma unroll
      for (int j = 0; j < 4; ++j) {
        const float rg = fast_sigmoid(rs[j] + rbv);
        const float zg = fast_sigmoid(zs[j] + zbv);
        const float ng = fast_tanh(nx[j] + nxb + rg * (nh[j] + nhb));
        const float hn = (1.f - zg) * ng + zg * hreg[j];
        hreg[j] = hn; hnv[j] = hn;
      }
      yshare[h][lane] = hnv;
#pragma unroll
      for (int j = 0; j < 4; ++j) {
        _Float16 hf = (_Float16)hnv[j];
        unsigned us = (unsigned)__builtin_bit_cast(unsigned short, hf);
        unsigned other = (unsigned)__shfl_xor((int)us, 1);
        if ((lane & 1) == 0)
          stw(hdst + (long)(((er0 + j) * HH) + col) * 2, us | (other << 16));
      }
      vdrain();                          // this wave's h-stores visible (L3)
      if (lane == 0)
        stw(myf + (rank * 2 + wid) * 16, (unsigned)(t + 1));   // EARLY flag
    }
    __syncthreads();   // (B): yshare visible for waves 2/3

    if (layer == 0) {
      if (wid == 2) {
        // ring stores of step t-1 already drained by this step's load-wait
        stw(l0if + rank * 16, (unsigned)t);                // slots <= t valid
        if (t >= RING - 1) {                               // lazy back-pressure
          const int need = t - (RING - 1);
          if (lb < need) {
            int sl = 0;
            for (;;) {
              unsigned f = ldflag(prog + (lane & 31) * 16);
              if (__ballot((int)f >= need + 16) == ~0ull) { lb = need + 16; break; }
              if (__ballot((int)f >= need) == ~0ull) { lb = need; break; }
              backoff_sleep(sl); ++sl;
            }
          }
        }
        char* rbase = (char*)(hist + (long)((t + 1) & (RING - 1)) * NBH);
#pragma unroll
        for (int h2 = 0; h2 < 2; ++h2) {
          f32x4 v = yshare[h2][lane];
          const int coln = rank * 32 + h2 * 16 + lcol;
#pragma unroll
          for (int j = 0; j < 4; ++j) {
            _Float16 hf = (_Float16)v[j];
            unsigned us = (unsigned)__builtin_bit_cast(unsigned short, hf);
            unsigned other = (unsigned)__shfl_xor((int)us, 1);
            if ((lane & 1) == 0)
              stw(rbase + (long)(((er0 + j) * HH) + coln) * 2, us | (other << 16));
          }
        }
      }
    } else {
      if (wid == 2 && lane == 0)
        stw(prog + rank * 16, (unsigned)t);                // L1 progress
      if (wid == 3) {
        float* yo = out + (long)t * NBH;
#pragma unroll
        for (int h2 = 0; h2 < 2; ++h2) {
          f32x4 v = yshare[h2][lane];
          const int coln = rank * 32 + h2 * 16 + lcol;
#pragma unroll
          for (int j = 0; j < 4; ++j) yo[(er0 + j) * HH + coln] = v[j];
        }
      }
    }
  }

  if (layer == 0 && wid == 2) {          // certify final ring slot
    vdrain();
    stw(l0if + rank * 16, (unsigned)TT);
  }
  if (wid < 2) {                         // final hidden states (f32 master)
#pragma unroll
    for (int j = 0; j < 4; ++j)
      out[(long)TT * NBH + (long)layer * NBH + (er0 + j) * HH + col] = hreg[j];
  }
}

// ---------------- launch ----------------
extern "C" void kernel_launch(void* const* d_in, const int* in_sizes, int n_in,
                              void* d_out, int out_size, void* d_ws, size_t ws_size,
                              hipStream_t stream) {
  const float* x   = (const float*)d_in[0];
  const float* h0  = (const float*)d_in[1];
  const float* Wx0 = (const float*)d_in[2];
  const float* bx0 = (const float*)d_in[3];
  const float* Wh0 = (const float*)d_in[4];
  const float* bh0 = (const float*)d_in[5];
  const float* Wx1 = (const float*)d_in[6];
  const float* bx1 = (const float*)d_in[7];
  const float* Wh1 = (const float*)d_in[8];
  const float* bh1 = (const float*)d_in[9];
  float* out = (float*)d_out;

  const long nTBH = (long)TT * BB * HH;
  const long nWP  = (long)192 * 64 * 64 * 8;

  char* p = (char*)d_ws;
  _Float16* x16   = (_Float16*)p;  p += nTBH * 2;              // 67.1 MB
  _Float16* w0p   = (_Float16*)p;  p += nWP * 2;               // 12.6 MB
  _Float16* w1p   = (_Float16*)p;  p += nWP * 2;               // 12.6 MB
  _Float16* hist  = (_Float16*)p;  p += (long)RING * NBH * 2;  // 4.2 MB
  _Float16* h0loc = (_Float16*)p;  p += 2 * (long)NBH * 2;     // 256 KB
  _Float16* h1loc = (_Float16*)p;  p += 2 * (long)NBH * 2;     // 256 KB
  unsigned* bar   = (unsigned*)p;  p += 131072;                // 128 KB flags
  if ((size_t)(p - (char*)d_ws) > ws_size) {
    sentinel_kernel<<<1, 1, 0, stream>>>(out);
    return;
  }

  (void)hipMemsetAsync(bar, 0, 131072, stream);
  cvt_f32_f16_kernel<<<2048, 256, 0, stream>>>(x, x16, nTBH);
  cvt_wpack_kernel<<<3072, 256, 0, stream>>>(Wh0, Wx0, w0p);
  cvt_wpack_kernel<<<3072, 256, 0, stream>>>(Wh1, Wx1, w1p);
  init_hf_kernel<<<512, 256, 0, stream>>>(h0, h0loc, h1loc);

  void* args[] = {(void*)&x16, (void*)&w0p, (void*)&w1p,
                  (void*)&bx0, (void*)&bh0, (void*)&bx1, (void*)&bh1,
                  (void*)&h0, (void*)&h0loc, (void*)&h1loc, (void*)&hist,
                  (void*)&out, (void*)&bar};
  hipError_t e = hipLaunchCooperativeKernel((const void*)gru_persist,
                                            dim3(NWG), dim3(256), args, 0, stream);
  if (e != hipSuccess) {
    // 256 WGs at 1 WG/CU: co-resident on an idle device even without coop.
    gru_persist<<<NWG, 256, 0, stream>>>(x16, w0p, w1p, bx0, bh0, bx1, bh1,
                                         h0, h0loc, h1loc, hist, out, bar);
  }
}